// Round 11
// baseline (213.053 us; speedup 1.0000x reference)
//
#include <hip/hip_runtime.h>
#include <hip/hip_bf16.h>
#include <math.h>
#include <stdint.h>

#define N_TOKENS 16384
#define DIM 4096
#define NEXP 64

typedef const __attribute__((address_space(1))) void gvoid_t;
typedef __attribute__((address_space(3))) void svoid_t;

constexpr int TOK_BLK = 32;   // tokens per block (all 64 experts in-block)
constexpr int KC = 128;       // k per staged chunk
constexpr int NT = DIM / KC;  // 32 chunks
constexpr int LGP = 68;       // padded logits row stride (floats)

// ------------- K1 (fused): logits + softmax + top2 + sel + histogram -------------
// lane = k: lane = (tg2 = lane>>4) token-subgroup x (kl = lane&15) k-slot.
// Each thread: acc[8 tok][16 exp] partial dot over its k-slice; 4-stage
// shfl_xor butterfly over kl finishes the dot products (3% one-time cost).
// x: double-buffered LDS via global_load_lds, LINEAR layout; compute read is
//    stride-1 b128 (conflict-free), 1 read per token per 64 FMA instrs ->
//    LDS pipe ~25% (R4..R10 structures needed 1 B/FMA = >100% of LDS BW).
// W: global vector loads, 16-lane coalesced 256B, 4-way lane-duplicate; W
//    chunk = 64 exp x 256B = 16 KB -> L1-resident, shared by all 8 waves/CU.
// Block covers ALL 64 experts -> x read from HBM exactly once (split=1) and
// complete logits live in-block -> softmax/top2/hist fused here (k2 deleted).
__global__ __launch_bounds__(256, 2) void k1_fused(
    const float* __restrict__ x, const float* __restrict__ W,
    float* __restrict__ topw, int* __restrict__ sel, int* __restrict__ cnt) {
  __shared__ float xlds[2][TOK_BLK * KC];  // 2 x 16 KB
  __shared__ float lg[TOK_BLK * LGP];      // logits, padded rows (8.5 KB)
  __shared__ int hist[NEXP];
  const int tid = threadIdx.x;
  const int lane = tid & 63;
  const int wid = __builtin_amdgcn_readfirstlane(tid >> 6);  // wave 0..3
  const int tg2 = lane >> 4;  // token subgroup (8 tokens each)
  const int kl = lane & 15;   // k slot (16 floats -> float4 per slot)
  const int tok0 = blockIdx.x * TOK_BLK;

  float acc[8][16] = {};  // 128 VGPR

  // stage x[tok0..+31][kc..+127]: 4 glds/wave, 2 rows (512B) each, linear dest
  auto stage = [&](int b, int kc) {
#pragma unroll
    for (int q = 0; q < 4; ++q) {
      const int qq = wid * 4 + q;
      const float* src = x + (size_t)(tok0 + 2 * qq + (lane >> 5)) * DIM + kc +
                         4 * (lane & 31);
      float* dst = &xlds[b][qq * 256];
      __builtin_amdgcn_global_load_lds((gvoid_t*)src, (svoid_t*)dst, 16, 0, 0);
    }
  };

  stage(0, 0);
  __syncthreads();

  for (int t = 0; t < NT; ++t) {
    const int cur = t & 1;
    if (t + 1 < NT) stage(cur ^ 1, (t + 1) * KC);  // prefetch overlaps FMAs

    const float* xb = &xlds[cur][0];
#pragma unroll
    for (int h = 0; h < 2; ++h) {  // k-halves of the chunk
      float4 xq[8];
#pragma unroll
      for (int i = 0; i < 8; ++i)
        xq[i] = *(const float4*)(xb + (tg2 * 8 + i) * KC + h * 64 + 4 * kl);
      const int kb = t * KC + h * 64 + 4 * kl;
#pragma unroll
      for (int jh = 0; jh < 2; ++jh) {  // expert halves: keeps w4 live-set at 32
        float4 w4[8];
#pragma unroll
        for (int j = 0; j < 8; ++j)
          w4[j] =
              *(const float4*)(W + (size_t)(wid * 16 + jh * 8 + j) * DIM + kb);
#pragma unroll
        for (int j = 0; j < 8; ++j)
#pragma unroll
          for (int i = 0; i < 8; ++i) {
            acc[i][jh * 8 + j] = fmaf(xq[i].x, w4[j].x, acc[i][jh * 8 + j]);
            acc[i][jh * 8 + j] = fmaf(xq[i].y, w4[j].y, acc[i][jh * 8 + j]);
            acc[i][jh * 8 + j] = fmaf(xq[i].z, w4[j].z, acc[i][jh * 8 + j]);
            acc[i][jh * 8 + j] = fmaf(xq[i].w, w4[j].w, acc[i][jh * 8 + j]);
          }
      }
    }
    __syncthreads();  // drains stage glds; closes buffer reuse
  }

  // finish dot products: butterfly over the 16 k-lanes (static indices only)
#pragma unroll
  for (int m = 1; m <= 8; m <<= 1)
#pragma unroll
    for (int i = 0; i < 8; ++i)
#pragma unroll
      for (int j = 0; j < 16; ++j)
        acc[i][j] += __shfl_xor(acc[i][j], m, 64);

  if (tid < NEXP) hist[tid] = 0;
  // kl==0 lanes publish this wave's 16-expert slice of the logits
  if (kl == 0) {
#pragma unroll
    for (int i = 0; i < 8; ++i) {
      float* dst = lg + (tg2 * 8 + i) * LGP + wid * 16;
#pragma unroll
      for (int jq = 0; jq < 4; ++jq) {
        float4 o;
        o.x = acc[i][jq * 4 + 0];
        o.y = acc[i][jq * 4 + 1];
        o.z = acc[i][jq * 4 + 2];
        o.w = acc[i][jq * 4 + 3];
        *(float4*)(dst + jq * 4) = o;
      }
    }
  }
  __syncthreads();

  // softmax + top2 per token (threads 0..31), then histogram
  if (tid < TOK_BLK) {
    const float* row = lg + tid * LGP;
    float4 v[16];
#pragma unroll
    for (int c = 0; c < 16; ++c) v[c] = *(const float4*)(row + c * 4);

    float v0 = -INFINITY, v1 = -INFINITY;
    int i0 = 0, i1 = 0;
#define TOP2_STEP(val, idx)                                  \
  {                                                          \
    const float vv = (val);                                  \
    const int ee = (idx);                                    \
    if (vv > v0) { v1 = v0; i1 = i0; v0 = vv; i0 = ee; }     \
    else if (vv > v1) { v1 = vv; i1 = ee; }                  \
  }
#pragma unroll
    for (int c = 0; c < 16; ++c) {
      TOP2_STEP(v[c].x, c * 4 + 0);
      TOP2_STEP(v[c].y, c * 4 + 1);
      TOP2_STEP(v[c].z, c * 4 + 2);
      TOP2_STEP(v[c].w, c * 4 + 3);
    }
#undef TOP2_STEP

    float denom = 0.f;
#pragma unroll
    for (int c = 0; c < 16; ++c) {
      denom += expf(v[c].x - v0);
      denom += expf(v[c].y - v0);
      denom += expf(v[c].z - v0);
      denom += expf(v[c].w - v0);
    }
    const float w0 = 1.0f / denom;  // expf(0) == 1 exactly
    const float w1 = expf(v1 - v0) / denom;

    const int t = tok0 + tid;
    topw[2 * t + 0] = w0;
    topw[2 * t + 1] = w1;
    sel[2 * t + 0] = i0;
    sel[2 * t + 1] = i1;
    atomicAdd(&hist[i0], 1);
    atomicAdd(&hist[i1], 1);
  }
  __syncthreads();
  if (tid < NEXP) {
    const int h = hist[tid];
    if (h) atomicAdd(&cnt[(tok0 >> 7) * NEXP + tid], h);
  }
}

// -------- K3: expert totals (counts out), exclusive offsets, chunk bases --------
__global__ void k3_scan(const int* __restrict__ cnt, int* __restrict__ cb,
                        float* __restrict__ counts_out) {
  __shared__ int tot[NEXP];
  const int e = threadIdx.x;  // 64 threads
  int run = 0;
  for (int p = 0; p < 128; ++p) run += cnt[p * NEXP + e];
  tot[e] = run;
  counts_out[e] = (float)run;
  __syncthreads();
  int g = 0;
  for (int q = 0; q < e; ++q) g += tot[q];
  int r = g;
  for (int p = 0; p < 128; ++p) {
    cb[p * NEXP + e] = r;
    r += cnt[p * NEXP + e];
  }
}

// ---------------- K4: stable scatter (counting-sort permutation) ----------------
__global__ __launch_bounds__(256) void k4_scatter(const int* __restrict__ sel,
                                                  const int* __restrict__ cb,
                                                  float* __restrict__ gout) {
  __shared__ int wcnt[4 * NEXP];
  const int tid = threadIdx.x;
  const int s = blockIdx.x * 256 + tid;
  const int e = sel[s];
  const int lane = tid & 63;
  const int wv = tid >> 6;
  wcnt[tid] = 0;
  __syncthreads();

  unsigned long long mask = ~0ull;
#pragma unroll
  for (int b = 0; b < 6; ++b) {
    const unsigned long long bb = __ballot((e >> b) & 1);
    mask &= ((e >> b) & 1) ? bb : ~bb;
  }
  const unsigned long long below = mask & ((1ull << lane) - 1ull);
  const int wr = __popcll(below);
  if (wr == 0) wcnt[wv * NEXP + e] = __popcll(mask);
  __syncthreads();

  int base = cb[blockIdx.x * NEXP + e];
  for (int w2 = 0; w2 < wv; ++w2) base += wcnt[w2 * NEXP + e];
  gout[base + wr] = (float)s;
}

extern "C" void kernel_launch(void* const* d_in, const int* in_sizes, int n_in,
                              void* d_out, int out_size, void* d_ws, size_t ws_size,
                              hipStream_t stream) {
  const float* x = (const float*)d_in[0];
  const float* W = (const float*)d_in[1];
  float* out = (float*)d_out;

  int* sel = (int*)d_ws;
  int* cnt = sel + N_TOKENS * 2;
  int* cb = cnt + 128 * NEXP;

  hipMemsetAsync(cnt, 0, 128 * NEXP * sizeof(int), stream);
  hipLaunchKernelGGL(k1_fused, dim3(N_TOKENS / TOK_BLK), dim3(256), 0, stream,
                     x, W, out, sel, cnt);
  hipLaunchKernelGGL(k3_scan, dim3(1), dim3(64), 0, stream, cnt, cb,
                     out + 2 * N_TOKENS + 2 * N_TOKENS);
  hipLaunchKernelGGL(k4_scatter, dim3((2 * N_TOKENS) / 256), dim3(256), 0, stream,
                     sel, cb, out + 2 * N_TOKENS);
}

// Round 12
// 120.762 us; speedup vs baseline: 1.7642x; 1.7642x over previous
//
#include <hip/hip_runtime.h>
#include <hip/hip_bf16.h>
#include <math.h>
#include <stdint.h>

#define N_TOKENS 16384
#define DIM 4096
#define NEXP 64

typedef const __attribute__((address_space(1))) void gvoid_t;
typedef __attribute__((address_space(3))) void svoid_t;
typedef short bf16x8 __attribute__((ext_vector_type(8)));
typedef float f32x4 __attribute__((ext_vector_type(4)));

__device__ __forceinline__ unsigned short bf16_rn(float f) {
  unsigned u = __float_as_uint(f);
  u += 0x7fffu + ((u >> 16) & 1u);
  return (unsigned short)(u >> 16);
}
__device__ __forceinline__ float bf16_tof(unsigned short h) {
  return __uint_as_float(((unsigned)h) << 16);
}

// ---------------- K0: split W into bf16 hi + bf16 lo (1 MB, runs once) --------
__global__ __launch_bounds__(256) void k0_wsplit(const float* __restrict__ W,
                                                 unsigned short* __restrict__ hi,
                                                 unsigned short* __restrict__ lo) {
  const int i = (blockIdx.x * 256 + threadIdx.x) * 4;
  const float4 f = *(const float4*)(W + i);
  ushort4 h, l;
  h.x = bf16_rn(f.x); l.x = bf16_rn(f.x - bf16_tof(h.x));
  h.y = bf16_rn(f.y); l.y = bf16_rn(f.y - bf16_tof(h.y));
  h.z = bf16_rn(f.z); l.z = bf16_rn(f.z - bf16_tof(h.z));
  h.w = bf16_rn(f.w); l.w = bf16_rn(f.w - bf16_tof(h.w));
  *(ushort4*)(hi + i) = h;
  *(ushort4*)(lo + i) = l;
}

// ------- K1 (fused, MFMA): logits + softmax + top2 + sel + histogram ----------
// Double-bf16 GEMM: x@W^T = xhi@Whi^T + xlo@Whi^T + xhi@Wlo^T (lo*lo ~2e-6,
// dropped). MFMA 16x16x32_bf16; layouts (m89-verified family):
//   A: row=lane&15, k=(lane>>4)*8+j   B: col=lane&15, k same
//   D: col=lane&15, row=(lane>>4)*4+reg
// Block = 64 tokens x ALL 64 experts (x read from HBM exactly once). Wave =
// 16 tokens x 4 N-tiles; acc = 4 x f32x4 = 16 VGPR. Kernel is HBM-streaming
// bound (~41us floor); MFMA+LDS+cvt all <60% of the per-chunk HBM time.
// x staged fp32 via global_load_lds, slot-XOR s^(row&15) (8 lanes/bank-group
// = byte floor); W hi/lo staged with s^(row&7). Rule-21 source-side swizzle,
// linear LDS dest. Double-buffered; stage(t+1) issued before compute(t).
__global__ __launch_bounds__(256, 2) void k1_fused(
    const float* __restrict__ x, const unsigned short* __restrict__ Whi,
    const unsigned short* __restrict__ Wlo, float* __restrict__ topw,
    int* __restrict__ sel, int* __restrict__ cnt) {
  __shared__ __align__(16) unsigned char smem[65536];
  __shared__ int hist[NEXP];
  float* const xz0 = (float*)smem;                              // 16 KB
  float* const xz1 = (float*)(smem + 16384);                    // 16 KB
  unsigned short* const whi0 = (unsigned short*)(smem + 32768); // 8 KB
  unsigned short* const whi1 = (unsigned short*)(smem + 40960);
  unsigned short* const wlo0 = (unsigned short*)(smem + 49152);
  unsigned short* const wlo1 = (unsigned short*)(smem + 57344);
  float* const lg = (float*)smem;  // overlay, used after the K-loop

  const int tid = threadIdx.x;
  const int lane = tid & 63;
  const int wid = __builtin_amdgcn_readfirstlane(tid >> 6);  // wave 0..3
  const int tok0 = blockIdx.x * 64;

  f32x4 acc[4] = {};  // 4 N-tiles x 4 rows

  // stage x[tok0..+63][kc..+63] (fp32): 4 glds/wave (1KB: 4 rows x 16 slots)
  auto stage_x = [&](float* xd, int kc) {
#pragma unroll
    for (int q = 0; q < 4; ++q) {
      const int r0 = wid * 16 + q * 4;        // wave-uniform row base
      const int row = r0 + (lane >> 4);       // block-local token row
      const int s = (lane & 15) ^ (row & 15); // logical slot for this dest
      const float* src = x + (size_t)(tok0 + row) * DIM + kc + 4 * s;
      __builtin_amdgcn_global_load_lds((gvoid_t*)src, (svoid_t*)(xd + r0 * 64),
                                       16, 0, 0);
    }
  };
  // stage Whi/Wlo[0..63][kc..+63] (bf16): 2+2 glds/wave (1KB: 8 rows x 8 slots)
  auto stage_w = [&](unsigned short* hd, unsigned short* ld, int kc) {
#pragma unroll
    for (int q = 0; q < 2; ++q) {
      const int r0 = wid * 16 + q * 8;      // wave-uniform row base
      const int row = r0 + (lane >> 3);
      const int s = (lane & 7) ^ (row & 7);
      const unsigned short* sh = Whi + (size_t)row * DIM + kc + 8 * s;
      const unsigned short* sl = Wlo + (size_t)row * DIM + kc + 8 * s;
      __builtin_amdgcn_global_load_lds((gvoid_t*)sh, (svoid_t*)(hd + r0 * 64),
                                       16, 0, 0);
      __builtin_amdgcn_global_load_lds((gvoid_t*)sl, (svoid_t*)(ld + r0 * 64),
                                       16, 0, 0);
    }
  };

  stage_x(xz0, 0);
  stage_w(whi0, wlo0, 0);
  __syncthreads();  // vmcnt drained at barrier

  const int r = lane & 15;   // A row within wave tile / B col within N-tile
  const int g = lane >> 4;   // k-group
  for (int t = 0; t < 64; ++t) {
    float* xc = (t & 1) ? xz1 : xz0;
    unsigned short* hc = (t & 1) ? whi1 : whi0;
    unsigned short* lc = (t & 1) ? wlo1 : wlo0;
    if (t + 1 < 64) {  // prefetch overlaps compute
      stage_x((t & 1) ? xz0 : xz1, (t + 1) * 64);
      stage_w((t & 1) ? whi0 : whi1, (t & 1) ? wlo0 : wlo1, (t + 1) * 64);
    }

#pragma unroll
    for (int h = 0; h < 2; ++h) {  // two K=32 MFMA steps per 64-k chunk
      const int arow = wid * 16 + r;
      const int s0 = h * 8 + 2 * g;  // first 16B slot of lane's 8 floats
      const float4 fa = *(const float4*)(xc + arow * 64 + 4 * (s0 ^ r));
      const float4 fb = *(const float4*)(xc + arow * 64 + 4 * ((s0 + 1) ^ r));
      const float fv[8] = {fa.x, fa.y, fa.z, fa.w, fb.x, fb.y, fb.z, fb.w};
      bf16x8 Ahi, Alo;
#pragma unroll
      for (int j = 0; j < 8; ++j) {
        const unsigned short hb = bf16_rn(fv[j]);
        Ahi[j] = (short)hb;
        Alo[j] = (short)bf16_rn(fv[j] - bf16_tof(hb));
      }
      const int ws = h * 4 + g;  // logical 8-bf16 slot in W rows
#pragma unroll
      for (int nt = 0; nt < 4; ++nt) {
        const int wrow = nt * 16 + r;
        const int wadr = wrow * 64 + 8 * (ws ^ (wrow & 7));
        const bf16x8 Bhi = *(const bf16x8*)(hc + wadr);
        const bf16x8 Blo = *(const bf16x8*)(lc + wadr);
        acc[nt] = __builtin_amdgcn_mfma_f32_16x16x32_bf16(Ahi, Bhi, acc[nt], 0, 0, 0);
        acc[nt] = __builtin_amdgcn_mfma_f32_16x16x32_bf16(Alo, Bhi, acc[nt], 0, 0, 0);
        acc[nt] = __builtin_amdgcn_mfma_f32_16x16x32_bf16(Ahi, Blo, acc[nt], 0, 0, 0);
      }
    }
    __syncthreads();  // drains stage glds; closes buffer reuse
  }

  // D layout: col(expert within tile)=lane&15, row(token)= (lane>>4)*4+reg
  if (tid < NEXP) hist[tid] = 0;
#pragma unroll
  for (int nt = 0; nt < 4; ++nt)
#pragma unroll
    for (int rg = 0; rg < 4; ++rg) {
      const int trow = wid * 16 + (lane >> 4) * 4 + rg;
      lg[trow * 68 + nt * 16 + (lane & 15)] = acc[nt][rg];
    }
  __syncthreads();

  // softmax + top2 per token (threads 0..63), then histogram
  if (tid < 64) {
    const float* rowp = lg + tid * 68;
    float4 v[16];
#pragma unroll
    for (int c = 0; c < 16; ++c) v[c] = *(const float4*)(rowp + c * 4);

    float v0 = -INFINITY, v1 = -INFINITY;
    int i0 = 0, i1 = 0;
#define TOP2_STEP(val, idx)                                  \
  {                                                          \
    const float vv = (val);                                  \
    const int ee = (idx);                                    \
    if (vv > v0) { v1 = v0; i1 = i0; v0 = vv; i0 = ee; }     \
    else if (vv > v1) { v1 = vv; i1 = ee; }                  \
  }
#pragma unroll
    for (int c = 0; c < 16; ++c) {
      TOP2_STEP(v[c].x, c * 4 + 0);
      TOP2_STEP(v[c].y, c * 4 + 1);
      TOP2_STEP(v[c].z, c * 4 + 2);
      TOP2_STEP(v[c].w, c * 4 + 3);
    }
#undef TOP2_STEP

    float denom = 0.f;
#pragma unroll
    for (int c = 0; c < 16; ++c) {
      denom += expf(v[c].x - v0);
      denom += expf(v[c].y - v0);
      denom += expf(v[c].z - v0);
      denom += expf(v[c].w - v0);
    }
    const float w0 = 1.0f / denom;  // expf(0)==1 exactly
    const float w1 = expf(v1 - v0) / denom;

    const int tk = tok0 + tid;
    topw[2 * tk + 0] = w0;
    topw[2 * tk + 1] = w1;
    sel[2 * tk + 0] = i0;
    sel[2 * tk + 1] = i1;
    atomicAdd(&hist[i0], 1);
    atomicAdd(&hist[i1], 1);
  }
  __syncthreads();
  if (tid < NEXP) {
    const int h = hist[tid];
    if (h) atomicAdd(&cnt[(tok0 >> 7) * NEXP + tid], h);
  }
}

// -------- K3: expert totals (counts out), exclusive offsets, chunk bases --------
__global__ void k3_scan(const int* __restrict__ cnt, int* __restrict__ cb,
                        float* __restrict__ counts_out) {
  __shared__ int tot[NEXP];
  const int e = threadIdx.x;  // 64 threads
  int run = 0;
  for (int p = 0; p < 128; ++p) run += cnt[p * NEXP + e];
  tot[e] = run;
  counts_out[e] = (float)run;
  __syncthreads();
  int g = 0;
  for (int q = 0; q < e; ++q) g += tot[q];
  int r = g;
  for (int p = 0; p < 128; ++p) {
    cb[p * NEXP + e] = r;
    r += cnt[p * NEXP + e];
  }
}

// ---------------- K4: stable scatter (counting-sort permutation) ----------------
__global__ __launch_bounds__(256) void k4_scatter(const int* __restrict__ sel,
                                                  const int* __restrict__ cb,
                                                  float* __restrict__ gout) {
  __shared__ int wcnt[4 * NEXP];
  const int tid = threadIdx.x;
  const int s = blockIdx.x * 256 + tid;
  const int e = sel[s];
  const int lane = tid & 63;
  const int wv = tid >> 6;
  wcnt[tid] = 0;
  __syncthreads();

  unsigned long long mask = ~0ull;
#pragma unroll
  for (int b = 0; b < 6; ++b) {
    const unsigned long long bb = __ballot((e >> b) & 1);
    mask &= ((e >> b) & 1) ? bb : ~bb;
  }
  const unsigned long long below = mask & ((1ull << lane) - 1ull);
  const int wr = __popcll(below);
  if (wr == 0) wcnt[wv * NEXP + e] = __popcll(mask);
  __syncthreads();

  int base = cb[blockIdx.x * NEXP + e];
  for (int w2 = 0; w2 < wv; ++w2) base += wcnt[w2 * NEXP + e];
  gout[base + wr] = (float)s;
}

extern "C" void kernel_launch(void* const* d_in, const int* in_sizes, int n_in,
                              void* d_out, int out_size, void* d_ws, size_t ws_size,
                              hipStream_t stream) {
  const float* x = (const float*)d_in[0];
  const float* W = (const float*)d_in[1];
  float* out = (float*)d_out;

  unsigned short* whi_g = (unsigned short*)d_ws;        // 512 KB
  unsigned short* wlo_g = whi_g + NEXP * DIM;           // 512 KB
  int* sel = (int*)(wlo_g + NEXP * DIM);                // 128 KB
  int* cnt = sel + N_TOKENS * 2;                        // 32 KB
  int* cb = cnt + 128 * NEXP;                           // 32 KB

  hipMemsetAsync(cnt, 0, 128 * NEXP * sizeof(int), stream);
  hipLaunchKernelGGL(k0_wsplit, dim3((NEXP * DIM) / 1024), dim3(256), 0, stream,
                     W, whi_g, wlo_g);
  hipLaunchKernelGGL(k1_fused, dim3(N_TOKENS / 64), dim3(256), 0, stream,
                     x, whi_g, wlo_g, out, sel, cnt);
  hipLaunchKernelGGL(k3_scan, dim3(1), dim3(64), 0, stream, cnt, cb,
                     out + 2 * N_TOKENS + 2 * N_TOKENS);
  hipLaunchKernelGGL(k4_scatter, dim3((2 * N_TOKENS) / 256), dim3(256), 0, stream,
                     sel, cb, out + 2 * N_TOKENS);
}

// Round 13
// 114.161 us; speedup vs baseline: 1.8663x; 1.0578x over previous
//
#include <hip/hip_runtime.h>
#include <hip/hip_bf16.h>
#include <math.h>
#include <stdint.h>

#define N_TOKENS 16384
#define DIM 4096
#define NEXP 64

typedef const __attribute__((address_space(1))) void gvoid_t;
typedef __attribute__((address_space(3))) void svoid_t;
typedef short bf16x8 __attribute__((ext_vector_type(8)));
typedef float f32x4 __attribute__((ext_vector_type(4)));

constexpr int TOK_BLK = 32;  // tokens per block -> grid 512 = 2 blocks/CU

__device__ __forceinline__ unsigned short bf16_rn(float f) {
  unsigned u = __float_as_uint(f);
  u += 0x7fffu + ((u >> 16) & 1u);
  return (unsigned short)(u >> 16);
}
__device__ __forceinline__ float bf16_tof(unsigned short h) {
  return __uint_as_float(((unsigned)h) << 16);
}

// ------ K0: split W into bf16 hi + lo (1 MB, once) + zero cnt (no memset) ------
__global__ __launch_bounds__(256) void k0_wsplit(const float* __restrict__ W,
                                                 unsigned short* __restrict__ hi,
                                                 unsigned short* __restrict__ lo,
                                                 int* __restrict__ cnt) {
  const int i = (blockIdx.x * 256 + threadIdx.x) * 4;
  const float4 f = *(const float4*)(W + i);
  ushort4 h, l;
  h.x = bf16_rn(f.x); l.x = bf16_rn(f.x - bf16_tof(h.x));
  h.y = bf16_rn(f.y); l.y = bf16_rn(f.y - bf16_tof(h.y));
  h.z = bf16_rn(f.z); l.z = bf16_rn(f.z - bf16_tof(h.z));
  h.w = bf16_rn(f.w); l.w = bf16_rn(f.w - bf16_tof(h.w));
  *(ushort4*)(hi + i) = h;
  *(ushort4*)(lo + i) = l;
  if (blockIdx.x < 8) {  // zero cnt[64][128] (runs before k1 in-stream)
    int4* c4 = (int4*)cnt;
    c4[blockIdx.x * 256 + threadIdx.x] = make_int4(0, 0, 0, 0);
  }
}

// ------- K1 (fused, MFMA): logits + softmax + top2 + sel + histogram ----------
// Double-bf16 GEMM (xhi@Whi + xlo@Whi + xhi@Wlo; lo*lo dropped ~2e-6).
// R12 failure mode fixed here: grid 256 = 1 block/CU left the glds drain
// latency-exposed (Occ 11%, VALU 10%). Now TOK_BLK=32, grid 512 = 2 blocks/CU,
// and x goes DIRECT global->reg (per-lane A-fragment slice: 16 rows x 1 line
// per instr), prefetched one chunk ahead; LDS holds only W hi/lo (dbuf 32KB)
// + lg scratch (~41KB total). Wave = 16 tokens (th=wid>>1) x 32 experts
// (eh=wid&1, 2 N-tiles). MFMA 16x16x32_bf16, layouts m89-verified (R12 passed):
//   A row=lane&15 (token), k=(lane>>4)*8+j; B col=lane&15 (expert row of W);
//   D col=lane&15 (expert), row=(lane>>4)*4+reg (token).
__global__ __launch_bounds__(256, 2) void k1_fused(
    const float* __restrict__ x, const unsigned short* __restrict__ Whi,
    const unsigned short* __restrict__ Wlo, float* __restrict__ topw,
    int* __restrict__ sel, int* __restrict__ cnt) {
  __shared__ unsigned short wh[2][NEXP * 64];  // 2 x 8 KB
  __shared__ unsigned short wl[2][NEXP * 64];  // 2 x 8 KB
  __shared__ float lg[TOK_BLK * 68];           // 8.5 KB
  __shared__ int hist[NEXP];

  const int tid = threadIdx.x;
  const int lane = tid & 63;
  const int wid = __builtin_amdgcn_readfirstlane(tid >> 6);  // wave 0..3
  const int th = wid >> 1;  // token half (16 tokens)
  const int eh = wid & 1;   // expert half (32 experts)
  const int r = lane & 15;  // A token row / B expert col within tile
  const int g = lane >> 4;  // k-group
  const int tok0 = blockIdx.x * TOK_BLK;

  f32x4 acc[2] = {};  // 2 N-tiles

  // stage Whi/Wlo[0..63][kc..+63] (bf16): 2+2 glds/wave (1KB each: 8 rows x 8 slots)
  auto stage_w = [&](unsigned short* hd, unsigned short* ld, int kc) {
#pragma unroll
    for (int q = 0; q < 2; ++q) {
      const int r0 = wid * 16 + q * 8;  // wave-uniform row base
      const int row = r0 + (lane >> 3);
      const int s = (lane & 7) ^ (row & 7);  // rule-21 source-side involution
      __builtin_amdgcn_global_load_lds((gvoid_t*)(Whi + (size_t)row * DIM + kc + 8 * s),
                                       (svoid_t*)(hd + r0 * 64), 16, 0, 0);
      __builtin_amdgcn_global_load_lds((gvoid_t*)(Wlo + (size_t)row * DIM + kc + 8 * s),
                                       (svoid_t*)(ld + r0 * 64), 16, 0, 0);
    }
  };

  // this lane's x row base (A-fragment slice lives at +t*64 + h*32 + g*8)
  const float* xrow = x + (size_t)(tok0 + th * 16 + r) * DIM + g * 8;

  auto xload = [&](float4* xd, int t) {
    const float* p = xrow + t * 64;
    xd[0] = *(const float4*)(p);
    xd[1] = *(const float4*)(p + 4);
    xd[2] = *(const float4*)(p + 32);
    xd[3] = *(const float4*)(p + 36);
  };

  auto body = [&](int t, float4* xc, float4* xn, unsigned short* whc,
                  unsigned short* wlc, unsigned short* whn, unsigned short* wln) {
    if (t + 1 < 64) {
      xload(xn, t + 1);        // x prefetch -> regs (T14)
      stage_w(whn, wln, (t + 1) * 64);
    }
#pragma unroll
    for (int h = 0; h < 2; ++h) {  // two K=32 MFMA steps per 64-k chunk
      const float fv[8] = {xc[2 * h].x, xc[2 * h].y, xc[2 * h].z, xc[2 * h].w,
                           xc[2 * h + 1].x, xc[2 * h + 1].y, xc[2 * h + 1].z,
                           xc[2 * h + 1].w};
      bf16x8 Ahi, Alo;
#pragma unroll
      for (int j = 0; j < 8; ++j) {
        const unsigned short hb = bf16_rn(fv[j]);
        Ahi[j] = (short)hb;
        Alo[j] = (short)bf16_rn(fv[j] - bf16_tof(hb));
      }
      const int ws = h * 4 + g;  // logical 16B slot within W row
#pragma unroll
      for (int nt = 0; nt < 2; ++nt) {
        const int wrow = eh * 32 + nt * 16 + r;
        const int wadr = wrow * 64 + 8 * (ws ^ (wrow & 7));
        const bf16x8 Bhi = *(const bf16x8*)(whc + wadr);
        const bf16x8 Blo = *(const bf16x8*)(wlc + wadr);
        acc[nt] = __builtin_amdgcn_mfma_f32_16x16x32_bf16(Ahi, Bhi, acc[nt], 0, 0, 0);
        acc[nt] = __builtin_amdgcn_mfma_f32_16x16x32_bf16(Alo, Bhi, acc[nt], 0, 0, 0);
        acc[nt] = __builtin_amdgcn_mfma_f32_16x16x32_bf16(Ahi, Blo, acc[nt], 0, 0, 0);
      }
    }
    __syncthreads();  // drains glds+xn loads; closes buffer reuse
  };

  float4 xA[4], xB[4];
  xload(xA, 0);
  stage_w(wh[0], wl[0], 0);
  __syncthreads();

  for (int tt = 0; tt < 64; tt += 2) {
    body(tt, xA, xB, wh[0], wl[0], wh[1], wl[1]);
    body(tt + 1, xB, xA, wh[1], wl[1], wh[0], wl[0]);
  }

  // D: token = th*16 + g*4 + rg, expert = eh*32 + nt*16 + r
  if (tid < NEXP) hist[tid] = 0;
#pragma unroll
  for (int nt = 0; nt < 2; ++nt)
#pragma unroll
    for (int rg = 0; rg < 4; ++rg)
      lg[(th * 16 + g * 4 + rg) * 68 + eh * 32 + nt * 16 + r] = acc[nt][rg];
  __syncthreads();

  // softmax + top2 per token (threads 0..31), then histogram
  if (tid < TOK_BLK) {
    const float* rowp = lg + tid * 68;
    float4 v[16];
#pragma unroll
    for (int c = 0; c < 16; ++c) v[c] = *(const float4*)(rowp + c * 4);

    float v0 = -INFINITY, v1 = -INFINITY;
    int i0 = 0, i1 = 0;
#define TOP2_STEP(val, idx)                                  \
  {                                                          \
    const float vv = (val);                                  \
    const int ee = (idx);                                    \
    if (vv > v0) { v1 = v0; i1 = i0; v0 = vv; i0 = ee; }     \
    else if (vv > v1) { v1 = vv; i1 = ee; }                  \
  }
#pragma unroll
    for (int c = 0; c < 16; ++c) {
      TOP2_STEP(v[c].x, c * 4 + 0);
      TOP2_STEP(v[c].y, c * 4 + 1);
      TOP2_STEP(v[c].z, c * 4 + 2);
      TOP2_STEP(v[c].w, c * 4 + 3);
    }
#undef TOP2_STEP

    float denom = 0.f;
#pragma unroll
    for (int c = 0; c < 16; ++c) {
      denom += expf(v[c].x - v0);
      denom += expf(v[c].y - v0);
      denom += expf(v[c].z - v0);
      denom += expf(v[c].w - v0);
    }
    const float w0 = 1.0f / denom;  // expf(0)==1 exactly
    const float w1 = expf(v1 - v0) / denom;

    const int tk = tok0 + tid;
    topw[2 * tk + 0] = w0;
    topw[2 * tk + 1] = w1;
    sel[2 * tk + 0] = i0;
    sel[2 * tk + 1] = i1;
    atomicAdd(&hist[i0], 1);
    atomicAdd(&hist[i1], 1);
  }
  __syncthreads();
  if (tid < NEXP) {
    const int h = hist[tid];
    if (h) atomicAdd(&cnt[tid * 128 + (blockIdx.x >> 2)], h);  // cnt[e][chunk]
  }
}

// -------- K3: expert totals (counts out), exclusive offsets, chunk bases --------
// cnt layout [e][128 chunks] -> first pass vectorized int4.
__global__ void k3_scan(const int* __restrict__ cnt, int* __restrict__ cb,
                        float* __restrict__ counts_out) {
  __shared__ int tot[NEXP];
  const int e = threadIdx.x;  // 64 threads
  const int4* row4 = (const int4*)(cnt + e * 128);
  int run = 0;
#pragma unroll
  for (int q = 0; q < 32; ++q) {
    const int4 v = row4[q];
    run += v.x + v.y + v.z + v.w;
  }
  tot[e] = run;
  counts_out[e] = (float)run;
  __syncthreads();
  int g = 0;
  for (int q = 0; q < e; ++q) g += tot[q];
  int r = g;
  for (int p = 0; p < 128; ++p) {
    cb[p * NEXP + e] = r;
    r += cnt[e * 128 + p];
  }
}

// ---------------- K4: stable scatter (counting-sort permutation) ----------------
__global__ __launch_bounds__(256) void k4_scatter(const int* __restrict__ sel,
                                                  const int* __restrict__ cb,
                                                  float* __restrict__ gout) {
  __shared__ int wcnt[4 * NEXP];
  const int tid = threadIdx.x;
  const int s = blockIdx.x * 256 + tid;
  const int e = sel[s];
  const int lane = tid & 63;
  const int wv = tid >> 6;
  wcnt[tid] = 0;
  __syncthreads();

  unsigned long long mask = ~0ull;
#pragma unroll
  for (int b = 0; b < 6; ++b) {
    const unsigned long long bb = __ballot((e >> b) & 1);
    mask &= ((e >> b) & 1) ? bb : ~bb;
  }
  const unsigned long long below = mask & ((1ull << lane) - 1ull);
  const int wr = __popcll(below);
  if (wr == 0) wcnt[wv * NEXP + e] = __popcll(mask);
  __syncthreads();

  int base = cb[blockIdx.x * NEXP + e];
  for (int w2 = 0; w2 < wv; ++w2) base += wcnt[w2 * NEXP + e];
  gout[base + wr] = (float)s;
}

extern "C" void kernel_launch(void* const* d_in, const int* in_sizes, int n_in,
                              void* d_out, int out_size, void* d_ws, size_t ws_size,
                              hipStream_t stream) {
  const float* x = (const float*)d_in[0];
  const float* W = (const float*)d_in[1];
  float* out = (float*)d_out;

  unsigned short* whi_g = (unsigned short*)d_ws;  // 512 KB
  unsigned short* wlo_g = whi_g + NEXP * DIM;     // 512 KB
  int* sel = (int*)(wlo_g + NEXP * DIM);          // 128 KB
  int* cnt = sel + N_TOKENS * 2;                  // 32 KB (cnt[e][128])
  int* cb = cnt + 128 * NEXP;                     // 32 KB (cb[p][e])

  hipLaunchKernelGGL(k0_wsplit, dim3((NEXP * DIM) / 1024), dim3(256), 0, stream,
                     W, whi_g, wlo_g, cnt);
  hipLaunchKernelGGL(k1_fused, dim3(N_TOKENS / TOK_BLK), dim3(256), 0, stream,
                     x, whi_g, wlo_g, out, sel, cnt);
  hipLaunchKernelGGL(k3_scan, dim3(1), dim3(64), 0, stream, cnt, cb,
                     out + 2 * N_TOKENS + 2 * N_TOKENS);
  hipLaunchKernelGGL(k4_scatter, dim3((2 * N_TOKENS) / 256), dim3(256), 0, stream,
                     sel, cb, out + 2 * N_TOKENS);
}